// Round 1
// baseline (1384.592 us; speedup 1.0000x reference)
//
#include <hip/hip_runtime.h>
#include <hip/hip_bf16.h>
#include <math.h>

// ---------------------------------------------------------------------------
// ChaosSSMCore: selective diag-SSM
//   B=128, T=2048, D=256, M = B*T = 262144
//   delta = softplus(x @ Wd^T); decay = exp(-delta*exp(log_a))
//   update = delta * sigmoid(x @ Ws^T) * (x @ Wi^T)
//   states = scan(decay, update);  y = states * silu(x @ Wg^T)
//   out = y @ Wo^T
// ---------------------------------------------------------------------------

typedef __attribute__((ext_vector_type(8))) short s16x8;
typedef __attribute__((ext_vector_type(4))) float f32x4;

#define D_DIM 256
#define T_DIM 2048
#define B_DIM 128
#define M_DIM (B_DIM * T_DIM)   // 262144
#define NCHUNK 16
#define CLEN 128                 // T / NCHUNK

__device__ __forceinline__ unsigned short f2bf(float f) {
    union { float f; unsigned int u; } v; v.f = f;
    unsigned int r = v.u + 0x7fffu + ((v.u >> 16) & 1u);   // RNE
    return (unsigned short)(r >> 16);
}
__device__ __forceinline__ float bf2f(unsigned short s) {
    union { unsigned int u; float f; } v; v.u = ((unsigned int)s) << 16;
    return v.f;
}

// --------------------------- prep: cast weights ---------------------------
// Wb slabs (each 65536 bf16): 0=W_delta 1=W_select 2=W_in 3=W_gate 4=W_out
__global__ __launch_bounds__(256) void prep_kernel(
    const float* __restrict__ W_in, const float* __restrict__ W_select,
    const float* __restrict__ W_gate, const float* __restrict__ W_out,
    const float* __restrict__ W_delta, const float* __restrict__ log_a,
    unsigned short* __restrict__ Wb, float* __restrict__ ea)
{
    int i = blockIdx.x * 256 + threadIdx.x;
    if (i < 5 * 65536) {
        int s = i >> 16, j = i & 65535;
        const float* src = (s == 0) ? W_delta : (s == 1) ? W_select
                         : (s == 2) ? W_in    : (s == 3) ? W_gate : W_out;
        Wb[i] = f2bf(src[j]);
    } else if (i < 5 * 65536 + 256) {
        int j = i - 5 * 65536;
        ea[j] = expf(log_a[j]);
    }
}

// --------------------------- gemm_a: 4 projections + elementwise ----------
// block tile: 64 (m) x 64 (n) for each of 4 W's. 4 waves in 2x2 grid,
// each wave 32x32 per W. MFMA 16x16x32 bf16.
__global__ __launch_bounds__(256) void gemm_a_kernel(
    const float* __restrict__ x, const unsigned short* __restrict__ Wb,
    const float* __restrict__ ea,
    float* __restrict__ decay, float* __restrict__ update,
    unsigned short* __restrict__ gate)
{
    // bijective XCD swizzle: nwg = 16384 (divisible by 8)
    int bid = blockIdx.x;
    int wg  = (bid & 7) * (16384 / 8) + (bid >> 3);
    int mtile = wg >> 2;          // 4096 m-tiles of 64 rows
    int ntile = wg & 3;           // 4 n-tiles of 64 cols
    int tid  = threadIdx.x;
    int lane = tid & 63, wid = tid >> 6;
    int wr = wid >> 1, wc = wid & 1;
    int m0 = mtile * 64 + wr * 32;
    int n0 = ntile * 64 + wc * 32;
    int l16 = lane & 15;
    int lk  = (lane >> 4) * 8;

    f32x4 acc[4][2][2] = {};  // [W][mfrag][nfrag]

    for (int ks = 0; ks < 8; ++ks) {
        int kb = ks * 32 + lk;
        // A fragments: x rows, fp32 -> bf16
        s16x8 afr[2];
#pragma unroll
        for (int mf = 0; mf < 2; ++mf) {
            const float* xp = x + (size_t)(m0 + mf * 16 + l16) * D_DIM + kb;
            float4 p0 = *(const float4*)xp;
            float4 p1 = *(const float4*)(xp + 4);
            s16x8 a;
            a[0] = (short)f2bf(p0.x); a[1] = (short)f2bf(p0.y);
            a[2] = (short)f2bf(p0.z); a[3] = (short)f2bf(p0.w);
            a[4] = (short)f2bf(p1.x); a[5] = (short)f2bf(p1.y);
            a[6] = (short)f2bf(p1.z); a[7] = (short)f2bf(p1.w);
            afr[mf] = a;
        }
#pragma unroll
        for (int w = 0; w < 4; ++w) {
#pragma unroll
            for (int nf = 0; nf < 2; ++nf) {
                const unsigned short* wp =
                    Wb + ((size_t)w << 16) + (size_t)(n0 + nf * 16 + l16) * D_DIM + kb;
                s16x8 b = *(const s16x8*)wp;
#pragma unroll
                for (int mf = 0; mf < 2; ++mf)
                    acc[w][mf][nf] = __builtin_amdgcn_mfma_f32_16x16x32_bf16(
                        afr[mf], b, acc[w][mf][nf], 0, 0, 0);
            }
        }
    }

    // epilogue: C/D layout col = lane&15, row = (lane>>4)*4 + j
    int r0 = (lane >> 4) * 4;
#pragma unroll
    for (int mf = 0; mf < 2; ++mf) {
#pragma unroll
        for (int nf = 0; nf < 2; ++nf) {
            int n = n0 + nf * 16 + l16;
            float ean = ea[n];
#pragma unroll
            for (int j = 0; j < 4; ++j) {
                int m = m0 + mf * 16 + r0 + j;
                size_t off = (size_t)m * D_DIM + n;
                float ad = acc[0][mf][nf][j];
                float as = acc[1][mf][nf][j];
                float ai = acc[2][mf][nf][j];
                float ag = acc[3][mf][nf][j];
                float delta = (ad > 20.f) ? ad : log1pf(expf(ad));
                float dec = expf(-delta * ean);
                float sel = 1.f / (1.f + expf(-as));
                float upd = delta * sel * ai;
                float g   = ag / (1.f + expf(-ag));   // silu
                decay[off]  = dec;
                update[off] = upd;
                gate[off]   = f2bf(g);
            }
        }
    }
}

// --------------------------- scan pass 1: chunk summaries ------------------
__global__ __launch_bounds__(256) void scan1_kernel(
    const float* __restrict__ decay, const float* __restrict__ update,
    float* __restrict__ cA, float* __restrict__ cS)
{
    int b = blockIdx.x >> 4;       // 128 batches
    int c = blockIdx.x & 15;       // 16 chunks
    int d = threadIdx.x;
    size_t base = ((size_t)b * T_DIM + (size_t)c * CLEN) * D_DIM + d;
    float A = 1.f, S = 0.f;
#pragma unroll 4
    for (int t = 0; t < CLEN; ++t) {
        float dc = decay[base + (size_t)t * D_DIM];
        float up = update[base + (size_t)t * D_DIM];
        A *= dc;
        S = dc * S + up;
    }
    int idx = (b * NCHUNK + c) * D_DIM + d;
    cA[idx] = A;
    cS[idx] = S;
}

// --------------------------- scan pass 2: chunk carries --------------------
__global__ __launch_bounds__(256) void scan2_kernel(
    const float* __restrict__ cA, const float* __restrict__ cS,
    float* __restrict__ carry)
{
    int b = blockIdx.x;
    int d = threadIdx.x;
    float s = 0.f;
    for (int c = 0; c < NCHUNK; ++c) {
        int idx = (b * NCHUNK + c) * D_DIM + d;
        carry[idx] = s;                 // state entering chunk c
        s = cA[idx] * s + cS[idx];
    }
}

// --------------------------- scan pass 3: final states + gate --------------
__global__ __launch_bounds__(256) void scan3_kernel(
    const float* __restrict__ decay, const float* __restrict__ update,
    const unsigned short* __restrict__ gate, const float* __restrict__ carry,
    unsigned short* __restrict__ y)
{
    int b = blockIdx.x >> 4;
    int c = blockIdx.x & 15;
    int d = threadIdx.x;
    size_t base = ((size_t)b * T_DIM + (size_t)c * CLEN) * D_DIM + d;
    float s = carry[(b * NCHUNK + c) * D_DIM + d];
#pragma unroll 4
    for (int t = 0; t < CLEN; ++t) {
        size_t off = base + (size_t)t * D_DIM;
        float dc = decay[off];
        float up = update[off];
        s = dc * s + up;
        float g = bf2f(gate[off]);
        y[off] = f2bf(s * g);
    }
}

// --------------------------- gemm_o: output projection ---------------------
__global__ __launch_bounds__(256) void gemm_o_kernel(
    const unsigned short* __restrict__ y, const unsigned short* __restrict__ Wo,
    float* __restrict__ out)
{
    int bid = blockIdx.x;
    int wg  = (bid & 7) * (16384 / 8) + (bid >> 3);
    int mtile = wg >> 2;
    int ntile = wg & 3;
    int tid  = threadIdx.x;
    int lane = tid & 63, wid = tid >> 6;
    int wr = wid >> 1, wc = wid & 1;
    int m0 = mtile * 64 + wr * 32;
    int n0 = ntile * 64 + wc * 32;
    int l16 = lane & 15;
    int lk  = (lane >> 4) * 8;

    f32x4 acc[2][2] = {};

    for (int ks = 0; ks < 8; ++ks) {
        int kb = ks * 32 + lk;
        s16x8 afr[2];
#pragma unroll
        for (int mf = 0; mf < 2; ++mf)
            afr[mf] = *(const s16x8*)(y + (size_t)(m0 + mf * 16 + l16) * D_DIM + kb);
#pragma unroll
        for (int nf = 0; nf < 2; ++nf) {
            s16x8 b = *(const s16x8*)(Wo + (size_t)(n0 + nf * 16 + l16) * D_DIM + kb);
#pragma unroll
            for (int mf = 0; mf < 2; ++mf)
                acc[mf][nf] = __builtin_amdgcn_mfma_f32_16x16x32_bf16(
                    afr[mf], b, acc[mf][nf], 0, 0, 0);
        }
    }

    int r0 = (lane >> 4) * 4;
#pragma unroll
    for (int mf = 0; mf < 2; ++mf)
#pragma unroll
        for (int nf = 0; nf < 2; ++nf) {
            int n = n0 + nf * 16 + l16;
#pragma unroll
            for (int j = 0; j < 4; ++j) {
                int m = m0 + mf * 16 + r0 + j;
                out[(size_t)m * D_DIM + n] = acc[mf][nf][j];
            }
        }
}

// ---------------------------------------------------------------------------
extern "C" void kernel_launch(void* const* d_in, const int* in_sizes, int n_in,
                              void* d_out, int out_size, void* d_ws, size_t ws_size,
                              hipStream_t stream)
{
    const float* x        = (const float*)d_in[0];
    const float* W_in     = (const float*)d_in[1];
    const float* W_select = (const float*)d_in[2];
    const float* W_gate   = (const float*)d_in[3];
    const float* W_out    = (const float*)d_in[4];
    const float* W_delta  = (const float*)d_in[5];
    const float* log_a    = (const float*)d_in[6];
    float* out = (float*)d_out;

    char* ws = (char*)d_ws;
    const size_t MB = 1ull << 20;
    unsigned short* Wb    = (unsigned short*)(ws);              // 640 KB
    float*          ea    = (float*)(ws + 655360);              // 1 KB
    float*          decay = (float*)(ws + 1 * MB);               // 256 MB
    float*          update= (float*)(ws + 257 * MB);             // 256 MB
    unsigned short* gate  = (unsigned short*)(ws + 513 * MB);    // 128 MB
    unsigned short* yb    = (unsigned short*)(ws + 641 * MB);    // 128 MB
    float*          cA    = (float*)(ws + 769 * MB);             // 2 MB
    float*          cS    = (float*)(ws + 771 * MB);             // 2 MB
    float*          carry = (float*)(ws + 773 * MB);             // 2 MB
    // total: 775 MB

    prep_kernel<<<1281, 256, 0, stream>>>(W_in, W_select, W_gate, W_out,
                                          W_delta, log_a, Wb, ea);
    gemm_a_kernel<<<16384, 256, 0, stream>>>(x, Wb, ea, decay, update, gate);
    scan1_kernel<<<B_DIM * NCHUNK, 256, 0, stream>>>(decay, update, cA, cS);
    scan2_kernel<<<B_DIM, 256, 0, stream>>>(cA, cS, carry);
    scan3_kernel<<<B_DIM * NCHUNK, 256, 0, stream>>>(decay, update, gate, carry, yb);
    gemm_o_kernel<<<16384, 256, 0, stream>>>(yb, Wb + 4 * 65536, out);
}

// Round 2
// 961.284 us; speedup vs baseline: 1.4404x; 1.4404x over previous
//
#include <hip/hip_runtime.h>
#include <hip/hip_bf16.h>
#include <hip/hip_fp16.h>
#include <math.h>

// ---------------------------------------------------------------------------
// ChaosSSMCore: selective diag-SSM
//   B=128, T=2048, D=256, M = B*T = 262144
//   delta = softplus(x @ Wd^T); decay = exp(-delta*exp(log_a))
//   update = delta * sigmoid(x @ Ws^T) * (x @ Wi^T)
//   states = scan(decay, update);  y = states * silu(x @ Wg^T)
//   out = y @ Wo^T
// ---------------------------------------------------------------------------

typedef __attribute__((ext_vector_type(8))) short s16x8;
typedef __attribute__((ext_vector_type(4))) float f32x4;
typedef __attribute__((ext_vector_type(4))) unsigned short u16x4;

#define D_DIM 256
#define T_DIM 2048
#define B_DIM 128
#define M_DIM (B_DIM * T_DIM)   // 262144
#define NCHUNK 16
#define CLEN 128                 // T / NCHUNK

__device__ __forceinline__ unsigned short f2bf(float f) {
    union { float f; unsigned int u; } v; v.f = f;
    unsigned int r = v.u + 0x7fffu + ((v.u >> 16) & 1u);   // RNE
    return (unsigned short)(r >> 16);
}
__device__ __forceinline__ float bf2f(unsigned short s) {
    union { unsigned int u; float f; } v; v.u = ((unsigned int)s) << 16;
    return v.f;
}

// --------------------------- prep: cast weights ---------------------------
// Wb slabs (each 65536 bf16): 0=W_delta 1=W_select 2=W_in 3=W_gate 4=W_out
__global__ __launch_bounds__(256) void prep_kernel(
    const float* __restrict__ W_in, const float* __restrict__ W_select,
    const float* __restrict__ W_gate, const float* __restrict__ W_out,
    const float* __restrict__ W_delta, const float* __restrict__ log_a,
    unsigned short* __restrict__ Wb, float* __restrict__ ea)
{
    int i = blockIdx.x * 256 + threadIdx.x;
    if (i < 5 * 65536) {
        int s = i >> 16, j = i & 65535;
        const float* src = (s == 0) ? W_delta : (s == 1) ? W_select
                         : (s == 2) ? W_in    : (s == 3) ? W_gate : W_out;
        Wb[i] = f2bf(src[j]);
    } else if (i < 5 * 65536 + 256) {
        int j = i - 5 * 65536;
        ea[j] = expf(log_a[j]);
    }
}

// --------------------------- xcast: x fp32 -> bf16 -------------------------
__global__ __launch_bounds__(256) void xcast_kernel(
    const float* __restrict__ x, unsigned short* __restrict__ xb)
{
    size_t i = ((size_t)blockIdx.x * 256 + threadIdx.x) * 8;
    float4 p0 = *(const float4*)(x + i);
    float4 p1 = *(const float4*)(x + i + 4);
    s16x8 a;
    a[0] = (short)f2bf(p0.x); a[1] = (short)f2bf(p0.y);
    a[2] = (short)f2bf(p0.z); a[3] = (short)f2bf(p0.w);
    a[4] = (short)f2bf(p1.x); a[5] = (short)f2bf(p1.y);
    a[6] = (short)f2bf(p1.z); a[7] = (short)f2bf(p1.w);
    *(s16x8*)(xb + i) = a;
}

// --------------------------- gemm_a: 4 projections + elementwise ----------
// block tile: 64 (m) x 64 (n) per W. 4 waves 2x2, each wave 32x32 per W.
// MFMA operands swapped: A-frag = W rows, B-frag = x rows
//   => D col (lane&15) = m, D rows = n (4 consecutive per reg) -> vector stores
__global__ __launch_bounds__(256) void gemm_a_kernel(
    const unsigned short* __restrict__ xb, const unsigned short* __restrict__ Wb,
    const float* __restrict__ ea,
    __half2* __restrict__ du, unsigned short* __restrict__ gate)
{
    int bid = blockIdx.x;
    int wg  = (bid & 7) * (16384 / 8) + (bid >> 3);   // bijective XCD swizzle
    int mtile = wg >> 2;
    int ntile = wg & 3;
    int tid  = threadIdx.x;
    int lane = tid & 63, wid = tid >> 6;
    int wr = wid >> 1, wc = wid & 1;
    int m0 = mtile * 64 + wr * 32;
    int n0 = ntile * 64 + wc * 32;
    int l16 = lane & 15;
    int lk  = (lane >> 4) * 8;

    f32x4 acc[4][2][2] = {};  // [W][mfrag][nfrag]

    for (int ks = 0; ks < 8; ++ks) {
        int kb = ks * 32 + lk;
        s16x8 xf[2];
#pragma unroll
        for (int mf = 0; mf < 2; ++mf)
            xf[mf] = *(const s16x8*)(xb + (size_t)(m0 + mf * 16 + l16) * D_DIM + kb);
#pragma unroll
        for (int w = 0; w < 4; ++w) {
#pragma unroll
            for (int nf = 0; nf < 2; ++nf) {
                const unsigned short* wp =
                    Wb + ((size_t)w << 16) + (size_t)(n0 + nf * 16 + l16) * D_DIM + kb;
                s16x8 wfr = *(const s16x8*)wp;
#pragma unroll
                for (int mf = 0; mf < 2; ++mf)
                    acc[w][mf][nf] = __builtin_amdgcn_mfma_f32_16x16x32_bf16(
                        wfr, xf[mf], acc[w][mf][nf], 0, 0, 0);
            }
        }
    }

    // epilogue: D col = lane&15 = m; D row = n = (lane>>4)*4 + j
    int r0 = (lane >> 4) * 4;
#pragma unroll
    for (int mf = 0; mf < 2; ++mf) {
        int m = m0 + mf * 16 + l16;
#pragma unroll
        for (int nf = 0; nf < 2; ++nf) {
            int n = n0 + nf * 16 + r0;
            float4 eav = *(const float4*)(ea + n);
            __half2 dv[4];
            u16x4 gv;
#pragma unroll
            for (int j = 0; j < 4; ++j) {
                float ad = acc[0][mf][nf][j];
                float as = acc[1][mf][nf][j];
                float ai = acc[2][mf][nf][j];
                float ag = acc[3][mf][nf][j];
                float e = __expf(ad);
                float delta = (ad > 15.f) ? ad : __logf(1.f + e);
                float ean = (j == 0) ? eav.x : (j == 1) ? eav.y : (j == 2) ? eav.z : eav.w;
                float dec = __expf(-delta * ean);
                float sel = 1.f / (1.f + __expf(-as));
                float upd = delta * sel * ai;
                float g   = ag / (1.f + __expf(-ag));   // silu
                dv[j] = __floats2half2_rn(dec, upd);
                gv[j] = f2bf(g);
            }
            *(f32x4*)(du + (size_t)m * D_DIM + n) = *(f32x4*)dv;
            *(u16x4*)(gate + (size_t)m * D_DIM + n) = gv;
        }
    }
}

// --------------------------- scan pass 1: chunk summaries ------------------
__global__ __launch_bounds__(256) void scan1_kernel(
    const __half2* __restrict__ du,
    float* __restrict__ cA, float* __restrict__ cS)
{
    int b = blockIdx.x >> 4;       // 128 batches
    int c = blockIdx.x & 15;       // 16 chunks
    int d = threadIdx.x;
    size_t base = ((size_t)b * T_DIM + (size_t)c * CLEN) * D_DIM + d;
    float A = 1.f, S = 0.f;
#pragma unroll 4
    for (int t = 0; t < CLEN; ++t) {
        __half2 v = du[base + (size_t)t * D_DIM];
        float dc = __low2float(v);
        float up = __high2float(v);
        A *= dc;
        S = fmaf(dc, S, up);
    }
    int idx = (b * NCHUNK + c) * D_DIM + d;
    cA[idx] = A;
    cS[idx] = S;
}

// --------------------------- scan pass 2: chunk carries --------------------
__global__ __launch_bounds__(256) void scan2_kernel(
    const float* __restrict__ cA, const float* __restrict__ cS,
    float* __restrict__ carry)
{
    int b = blockIdx.x;
    int d = threadIdx.x;
    float s = 0.f;
    for (int c = 0; c < NCHUNK; ++c) {
        int idx = (b * NCHUNK + c) * D_DIM + d;
        carry[idx] = s;                 // state entering chunk c
        s = fmaf(cA[idx], s, cS[idx]);
    }
}

// --------------------------- fused scan3 + out-projection ------------------
// block = (b, chunk): scans 128 t-rows (full D), builds y tile in LDS (bf16,
// chunk-XOR-swizzled), then computes out[128 x 256] = y @ Wo^T with MFMA.
__global__ __launch_bounds__(256) void scan_out_kernel(
    const __half2* __restrict__ du, const unsigned short* __restrict__ gate,
    const float* __restrict__ carry, const unsigned short* __restrict__ Wo,
    float* __restrict__ out)
{
    __shared__ unsigned short yls[128 * 256];   // 64 KB
    int b = blockIdx.x >> 4;
    int c = blockIdx.x & 15;
    int tid = threadIdx.x;

    // ---- phase 1: sequential scan, y -> LDS (swizzled 16B chunks) ----
    {
        int d = tid;
        size_t base = ((size_t)b * T_DIM + (size_t)c * CLEN) * D_DIM + d;
        float s = carry[(b * NCHUNK + c) * D_DIM + d];
        int dlo = d & 7, dch = d >> 3;
#pragma unroll 4
        for (int t = 0; t < CLEN; ++t) {
            __half2 v = du[base + (size_t)t * D_DIM];
            float dc = __low2float(v);
            float up = __high2float(v);
            s = fmaf(dc, s, up);
            float g = bf2f(gate[base + (size_t)t * D_DIM]);
            int off = t * 256 + ((dch ^ (t & 7)) << 3) + dlo;
            yls[off] = f2bf(s * g);
        }
    }
    __syncthreads();

    // ---- phase 2: out-tile GEMM, A-frag = Wo rows (global), B-frag = y (LDS)
    int lane = tid & 63, wid = tid >> 6;
    int l16 = lane & 15;
    int lkc = lane >> 4;            // k-subgroup 0..3
    int m0 = (wid >> 1) * 64;
    size_t rbase = (size_t)b * T_DIM + (size_t)c * CLEN;
    int r0 = lkc * 4;

    for (int nblk = 0; nblk < 2; ++nblk) {
        int n0 = (wid & 1) * 64 + nblk * 128;
        f32x4 acc[4][4] = {};
        for (int ks = 0; ks < 8; ++ks) {
            int kb = ks * 32 + lkc * 8;
            s16x8 yf[4];
#pragma unroll
            for (int mf = 0; mf < 4; ++mf) {
                int row = m0 + mf * 16 + l16;
                int chunk = (ks * 4 + lkc) ^ (row & 7);
                yf[mf] = *(const s16x8*)&yls[row * 256 + chunk * 8];
            }
#pragma unroll
            for (int nf = 0; nf < 4; ++nf) {
                s16x8 wfr = *(const s16x8*)(Wo + (size_t)(n0 + nf * 16 + l16) * D_DIM + kb);
#pragma unroll
                for (int mf = 0; mf < 4; ++mf)
                    acc[mf][nf] = __builtin_amdgcn_mfma_f32_16x16x32_bf16(
                        wfr, yf[mf], acc[mf][nf], 0, 0, 0);
            }
        }
        // D col = lane&15 = y row; D rows = n (4 consecutive) -> float4 stores
#pragma unroll
        for (int mf = 0; mf < 4; ++mf) {
            size_t rowg = rbase + m0 + mf * 16 + l16;
#pragma unroll
            for (int nf = 0; nf < 4; ++nf) {
                int n = n0 + nf * 16 + r0;
                *(f32x4*)(out + rowg * D_DIM + n) = acc[mf][nf];
            }
        }
    }
}

// ---------------------------------------------------------------------------
extern "C" void kernel_launch(void* const* d_in, const int* in_sizes, int n_in,
                              void* d_out, int out_size, void* d_ws, size_t ws_size,
                              hipStream_t stream)
{
    const float* x        = (const float*)d_in[0];
    const float* W_in     = (const float*)d_in[1];
    const float* W_select = (const float*)d_in[2];
    const float* W_gate   = (const float*)d_in[3];
    const float* W_out    = (const float*)d_in[4];
    const float* W_delta  = (const float*)d_in[5];
    const float* log_a    = (const float*)d_in[6];
    float* out = (float*)d_out;

    char* ws = (char*)d_ws;
    const size_t MB = 1ull << 20;
    unsigned short* Wb    = (unsigned short*)(ws);               // 640 KB
    float*          ea    = (float*)(ws + 655360);               // 1 KB
    unsigned short* xb    = (unsigned short*)(ws + 1 * MB);      // 128 MB
    __half2*        du    = (__half2*)(ws + 129 * MB);           // 256 MB
    unsigned short* gate  = (unsigned short*)(ws + 385 * MB);    // 128 MB
    float*          cA    = (float*)(ws + 513 * MB);             // 2 MB
    float*          cS    = (float*)(ws + 515 * MB);             // 2 MB
    float*          carry = (float*)(ws + 517 * MB);             // 2 MB
    // total: 519 MB

    prep_kernel<<<1281, 256, 0, stream>>>(W_in, W_select, W_gate, W_out,
                                          W_delta, log_a, Wb, ea);
    xcast_kernel<<<32768, 256, 0, stream>>>(x, xb);
    gemm_a_kernel<<<16384, 256, 0, stream>>>(xb, Wb, ea, du, gate);
    scan1_kernel<<<B_DIM * NCHUNK, 256, 0, stream>>>(du, cA, cS);
    scan2_kernel<<<B_DIM, 256, 0, stream>>>(cA, cS, carry);
    scan_out_kernel<<<B_DIM * NCHUNK, 256, 0, stream>>>(du, gate, carry,
                                                        Wb + 4 * 65536, out);
}

// Round 3
// 753.294 us; speedup vs baseline: 1.8380x; 1.2761x over previous
//
#include <hip/hip_runtime.h>
#include <hip/hip_bf16.h>
#include <hip/hip_fp16.h>
#include <math.h>

// ---------------------------------------------------------------------------
// ChaosSSMCore: selective diag-SSM
//   B=128, T=2048, D=256, M = B*T = 262144
//   delta = softplus(x @ Wd^T); decay = exp(-delta*exp(log_a))
//   update = delta * sigmoid(x @ Ws^T) * (x @ Wi^T)
//   states = scan(decay, update);  y = states * silu(x @ Wg^T)
//   out = y @ Wo^T
// ---------------------------------------------------------------------------

typedef __attribute__((ext_vector_type(8))) short s16x8;
typedef __attribute__((ext_vector_type(4))) float f32x4;
typedef __attribute__((ext_vector_type(4))) unsigned short u16x4;

#define D_DIM 256
#define T_DIM 2048
#define B_DIM 128
#define M_DIM (B_DIM * T_DIM)   // 262144
#define NCHUNK 16
#define CLEN 128                 // T / NCHUNK

__device__ __forceinline__ unsigned short f2bf(float f) {
    union { float f; unsigned int u; } v; v.f = f;
    unsigned int r = v.u + 0x7fffu + ((v.u >> 16) & 1u);   // RNE
    return (unsigned short)(r >> 16);
}
__device__ __forceinline__ float bf2f(unsigned short s) {
    union { unsigned int u; float f; } v; v.u = ((unsigned int)s) << 16;
    return v.f;
}
__device__ __forceinline__ void gload_lds16(const void* g, void* l) {
    __builtin_amdgcn_global_load_lds(
        (const __attribute__((address_space(1))) unsigned int*)g,
        (__attribute__((address_space(3))) unsigned int*)l, 16, 0, 0);
}

// --------------------------- prep: cast weights ---------------------------
// Wb slabs (each 65536 bf16): 0=W_delta 1=W_select 2=W_in 3=W_gate 4=W_out
__global__ __launch_bounds__(256) void prep_kernel(
    const float* __restrict__ W_in, const float* __restrict__ W_select,
    const float* __restrict__ W_gate, const float* __restrict__ W_out,
    const float* __restrict__ W_delta, const float* __restrict__ log_a,
    unsigned short* __restrict__ Wb, float* __restrict__ ea)
{
    int i = blockIdx.x * 256 + threadIdx.x;
    if (i < 5 * 65536) {
        int s = i >> 16, j = i & 65535;
        const float* src = (s == 0) ? W_delta : (s == 1) ? W_select
                         : (s == 2) ? W_in    : (s == 3) ? W_gate : W_out;
        Wb[i] = f2bf(src[j]);
    } else if (i < 5 * 65536 + 256) {
        int j = i - 5 * 65536;
        ea[j] = expf(log_a[j]);
    }
}

// --------------------------- xcast: x fp32 -> bf16 -------------------------
__global__ __launch_bounds__(256) void xcast_kernel(
    const float* __restrict__ x, unsigned short* __restrict__ xb)
{
    size_t i = ((size_t)blockIdx.x * 256 + threadIdx.x) * 8;
    float4 p0 = *(const float4*)(x + i);
    float4 p1 = *(const float4*)(x + i + 4);
    s16x8 a;
    a[0] = (short)f2bf(p0.x); a[1] = (short)f2bf(p0.y);
    a[2] = (short)f2bf(p0.z); a[3] = (short)f2bf(p0.w);
    a[4] = (short)f2bf(p1.x); a[5] = (short)f2bf(p1.y);
    a[6] = (short)f2bf(p1.z); a[7] = (short)f2bf(p1.w);
    *(s16x8*)(xb + i) = a;
}

// --------------------------- gemm_a: 4 projections + elementwise ----------
// block = 64m x 256n (all 4 Ws), 8 waves, wave = 64m x 32n per W.
// x-tile [64][256] bf16 staged once in LDS via global_load_lds (width 16),
// XOR-swizzled in 16B granules: granule' = granule ^ (row & 7)  (applied on
// the *global source address* at stage time, and on the LDS read address).
// MFMA operands: A = W rows, B = x rows -> D col(lane&15)=m, D regs = n.
__global__ __launch_bounds__(512, 2) void gemm_a_kernel(
    const unsigned short* __restrict__ xb, const unsigned short* __restrict__ Wb,
    const float* __restrict__ ea,
    __half2* __restrict__ du, unsigned short* __restrict__ gate)
{
    __shared__ unsigned short xls[64 * 256];   // 32 KB
    int bid = blockIdx.x;
    int wg  = (bid & 7) * (4096 / 8) + (bid >> 3);   // bijective XCD swizzle
    int mbase = wg * 64;
    int tid  = threadIdx.x;
    int lane = tid & 63, wid = tid >> 6;

    // ---- stage x-tile (each wave: 4 x 1KB chunks) ----
    {
        const unsigned short* xg = xb + (size_t)mbase * D_DIM;
#pragma unroll
        for (int i = 0; i < 4; ++i) {
            int o   = (wid * 4 + i) * 1024 + lane * 16;  // linear LDS byte off
            int row = o >> 9;                            // 512 B per row
            int gs  = (o >> 4) & 31;
            int g   = gs ^ (row & 7);                    // source granule
            gload_lds16(xg + row * D_DIM + g * 8,
                        ((char*)xls) + (wid * 4 + i) * 1024);
        }
    }
    __syncthreads();   // drains vmcnt(0)

    int l16 = lane & 15;
    int lk  = lane >> 4;            // 0..3
    int n0  = wid * 32;

    f32x4 acc[4][4][2] = {};        // [W][mf][nf]

    for (int ks = 0; ks < 8; ++ks) {
        int kb = ks * 32 + lk * 8;
        s16x8 xf[4];
#pragma unroll
        for (int mf = 0; mf < 4; ++mf) {
            int row = mf * 16 + l16;
            int g   = (ks * 4 + lk) ^ (row & 7);
            xf[mf] = *(const s16x8*)((const char*)xls + row * 512 + g * 16);
        }
#pragma unroll
        for (int w = 0; w < 4; ++w) {
#pragma unroll
            for (int nf = 0; nf < 2; ++nf) {
                s16x8 wfr = *(const s16x8*)(
                    Wb + ((size_t)w << 16) + (size_t)(n0 + nf * 16 + l16) * D_DIM + kb);
#pragma unroll
                for (int mf = 0; mf < 4; ++mf)
                    acc[w][mf][nf] = __builtin_amdgcn_mfma_f32_16x16x32_bf16(
                        wfr, xf[mf], acc[w][mf][nf], 0, 0, 0);
            }
        }
    }

    // epilogue: D col = lane&15 = m; D row = n = (lane>>4)*4 + j
    int r0 = lk * 4;
#pragma unroll
    for (int mf = 0; mf < 4; ++mf) {
        int m = mbase + mf * 16 + l16;
#pragma unroll
        for (int nf = 0; nf < 2; ++nf) {
            int n = n0 + nf * 16 + r0;
            float4 eav = *(const float4*)(ea + n);
            __half2 dv[4];
            u16x4 gv;
#pragma unroll
            for (int j = 0; j < 4; ++j) {
                float ad = acc[0][mf][nf][j];
                float as = acc[1][mf][nf][j];
                float ai = acc[2][mf][nf][j];
                float ag = acc[3][mf][nf][j];
                float e = __expf(ad);
                float delta = (ad > 15.f) ? ad : __logf(1.f + e);
                float ean = (j == 0) ? eav.x : (j == 1) ? eav.y : (j == 2) ? eav.z : eav.w;
                float dec = __expf(-delta * ean);
                float sel = 1.f / (1.f + __expf(-as));
                float upd = delta * sel * ai;
                float g   = ag / (1.f + __expf(-ag));   // silu
                dv[j] = __floats2half2_rn(dec, upd);
                gv[j] = f2bf(g);
            }
            *(f32x4*)(du + (size_t)m * D_DIM + n) = *(f32x4*)dv;
            *(u16x4*)(gate + (size_t)m * D_DIM + n) = gv;
        }
    }
}

// --------------------------- scan pass 1: chunk summaries ------------------
__global__ __launch_bounds__(256) void scan1_kernel(
    const __half2* __restrict__ du,
    float* __restrict__ cA, float* __restrict__ cS)
{
    int b = blockIdx.x >> 4;       // 128 batches
    int c = blockIdx.x & 15;       // 16 chunks
    int d = threadIdx.x;
    size_t base = ((size_t)b * T_DIM + (size_t)c * CLEN) * D_DIM + d;
    float A = 1.f, S = 0.f;
#pragma unroll 4
    for (int t = 0; t < CLEN; ++t) {
        __half2 v = du[base + (size_t)t * D_DIM];
        float dc = __low2float(v);
        float up = __high2float(v);
        A *= dc;
        S = fmaf(dc, S, up);
    }
    int idx = (b * NCHUNK + c) * D_DIM + d;
    cA[idx] = A;
    cS[idx] = S;
}

// --------------------------- scan pass 2: chunk carries --------------------
__global__ __launch_bounds__(256) void scan2_kernel(
    const float* __restrict__ cA, const float* __restrict__ cS,
    float* __restrict__ carry)
{
    int b = blockIdx.x;
    int d = threadIdx.x;
    float s = 0.f;
    for (int c = 0; c < NCHUNK; ++c) {
        int idx = (b * NCHUNK + c) * D_DIM + d;
        carry[idx] = s;                 // state entering chunk c
        s = fmaf(cA[idx], s, cS[idx]);
    }
}

// --------------------------- fused scan3 + out-projection ------------------
// block = (b, chunk): scans 128 t-rows (full D), builds y tile in LDS (bf16,
// chunk-XOR-swizzled), then computes out[128 x 256] = y @ Wo^T with MFMA.
__global__ __launch_bounds__(256) void scan_out_kernel(
    const __half2* __restrict__ du, const unsigned short* __restrict__ gate,
    const float* __restrict__ carry, const unsigned short* __restrict__ Wo,
    float* __restrict__ out)
{
    __shared__ unsigned short yls[128 * 256];   // 64 KB
    int b = blockIdx.x >> 4;
    int c = blockIdx.x & 15;
    int tid = threadIdx.x;

    // ---- phase 1: sequential scan, y -> LDS (swizzled 16B chunks) ----
    {
        int d = tid;
        size_t base = ((size_t)b * T_DIM + (size_t)c * CLEN) * D_DIM + d;
        float s = carry[(b * NCHUNK + c) * D_DIM + d];
        int dlo = d & 7, dch = d >> 3;
#pragma unroll 4
        for (int t = 0; t < CLEN; ++t) {
            __half2 v = du[base + (size_t)t * D_DIM];
            float dc = __low2float(v);
            float up = __high2float(v);
            s = fmaf(dc, s, up);
            float g = bf2f(gate[base + (size_t)t * D_DIM]);
            int off = t * 256 + ((dch ^ (t & 7)) << 3) + dlo;
            yls[off] = f2bf(s * g);
        }
    }
    __syncthreads();

    // ---- phase 2: out-tile GEMM, A-frag = Wo rows (global), B-frag = y (LDS)
    int lane = tid & 63, wid = tid >> 6;
    int l16 = lane & 15;
    int lkc = lane >> 4;            // k-subgroup 0..3
    int m0 = (wid >> 1) * 64;
    size_t rbase = (size_t)b * T_DIM + (size_t)c * CLEN;
    int r0 = lkc * 4;

    for (int nblk = 0; nblk < 2; ++nblk) {
        int n0 = (wid & 1) * 64 + nblk * 128;
        f32x4 acc[4][4] = {};
        for (int ks = 0; ks < 8; ++ks) {
            int kb = ks * 32 + lkc * 8;
            s16x8 yf[4];
#pragma unroll
            for (int mf = 0; mf < 4; ++mf) {
                int row = m0 + mf * 16 + l16;
                int chunk = (ks * 4 + lkc) ^ (row & 7);
                yf[mf] = *(const s16x8*)&yls[row * 256 + chunk * 8];
            }
#pragma unroll
            for (int nf = 0; nf < 4; ++nf) {
                s16x8 wfr = *(const s16x8*)(Wo + (size_t)(n0 + nf * 16 + l16) * D_DIM + kb);
#pragma unroll
                for (int mf = 0; mf < 4; ++mf)
                    acc[mf][nf] = __builtin_amdgcn_mfma_f32_16x16x32_bf16(
                        wfr, yf[mf], acc[mf][nf], 0, 0, 0);
            }
        }
        // D col = lane&15 = y row; D rows = n (4 consecutive) -> float4 stores
#pragma unroll
        for (int mf = 0; mf < 4; ++mf) {
            size_t rowg = rbase + m0 + mf * 16 + l16;
#pragma unroll
            for (int nf = 0; nf < 4; ++nf) {
                int n = n0 + nf * 16 + r0;
                *(f32x4*)(out + rowg * D_DIM + n) = acc[mf][nf];
            }
        }
    }
}

// ---------------------------------------------------------------------------
extern "C" void kernel_launch(void* const* d_in, const int* in_sizes, int n_in,
                              void* d_out, int out_size, void* d_ws, size_t ws_size,
                              hipStream_t stream)
{
    const float* x        = (const float*)d_in[0];
    const float* W_in     = (const float*)d_in[1];
    const float* W_select = (const float*)d_in[2];
    const float* W_gate   = (const float*)d_in[3];
    const float* W_out    = (const float*)d_in[4];
    const float* W_delta  = (const float*)d_in[5];
    const float* log_a    = (const float*)d_in[6];
    float* out = (float*)d_out;

    char* ws = (char*)d_ws;
    const size_t MB = 1ull << 20;
    unsigned short* Wb    = (unsigned short*)(ws);               // 640 KB
    float*          ea    = (float*)(ws + 655360);               // 1 KB
    unsigned short* xb    = (unsigned short*)(ws + 1 * MB);      // 128 MB
    __half2*        du    = (__half2*)(ws + 129 * MB);           // 256 MB
    unsigned short* gate  = (unsigned short*)(ws + 385 * MB);    // 128 MB
    float*          cA    = (float*)(ws + 513 * MB);             // 2 MB
    float*          cS    = (float*)(ws + 515 * MB);             // 2 MB
    float*          carry = (float*)(ws + 517 * MB);             // 2 MB
    // total: 519 MB

    prep_kernel<<<1281, 256, 0, stream>>>(W_in, W_select, W_gate, W_out,
                                          W_delta, log_a, Wb, ea);
    xcast_kernel<<<32768, 256, 0, stream>>>(x, xb);
    gemm_a_kernel<<<4096, 512, 0, stream>>>(xb, Wb, ea, du, gate);
    scan1_kernel<<<B_DIM * NCHUNK, 256, 0, stream>>>(du, cA, cS);
    scan2_kernel<<<B_DIM, 256, 0, stream>>>(cA, cS, carry);
    scan_out_kernel<<<B_DIM * NCHUNK, 256, 0, stream>>>(du, gate, carry,
                                                        Wb + 4 * 65536, out);
}

// Round 4
// 718.386 us; speedup vs baseline: 1.9274x; 1.0486x over previous
//
#include <hip/hip_runtime.h>
#include <hip/hip_bf16.h>
#include <hip/hip_fp16.h>
#include <math.h>

// ---------------------------------------------------------------------------
// ChaosSSMCore: selective diag-SSM
//   B=128, T=2048, D=256, M = B*T = 262144
//   delta = softplus(x @ Wd^T); decay = exp(-delta*exp(log_a))
//   update = delta * sigmoid(x @ Ws^T) * (x @ Wi^T)
//   states = scan(decay, update);  y = states * silu(x @ Wg^T)
//   out = y @ Wo^T
// ---------------------------------------------------------------------------

typedef __attribute__((ext_vector_type(8))) short s16x8;
typedef __attribute__((ext_vector_type(4))) float f32x4;
typedef __attribute__((ext_vector_type(4))) unsigned short u16x4;

#define D_DIM 256
#define T_DIM 2048
#define B_DIM 128
#define NCHUNK 16
#define CLEN 128                 // T / NCHUNK
#define ROWB 528                 // LDS row stride bytes (33 granules of 16B)

__device__ __forceinline__ unsigned short f2bf(float f) {
    union { float f; unsigned int u; } v; v.f = f;
    unsigned int r = v.u + 0x7fffu + ((v.u >> 16) & 1u);   // RNE
    return (unsigned short)(r >> 16);
}
__device__ __forceinline__ float bf2f(unsigned short s) {
    union { unsigned int u; float f; } v; v.u = ((unsigned int)s) << 16;
    return v.f;
}
__device__ __forceinline__ s16x8 cvt8(const float* xp) {
    float4 p0 = *(const float4*)xp;
    float4 p1 = *(const float4*)(xp + 4);
    s16x8 a;
    a[0] = (short)f2bf(p0.x); a[1] = (short)f2bf(p0.y);
    a[2] = (short)f2bf(p0.z); a[3] = (short)f2bf(p0.w);
    a[4] = (short)f2bf(p1.x); a[5] = (short)f2bf(p1.y);
    a[6] = (short)f2bf(p1.z); a[7] = (short)f2bf(p1.w);
    return a;
}

// --------------------------- prep: cast weights ---------------------------
// Wb slabs (each 65536 bf16): 0=W_delta 1=W_select 2=W_in 3=W_gate 4=W_out
__global__ __launch_bounds__(256) void prep_kernel(
    const float* __restrict__ W_in, const float* __restrict__ W_select,
    const float* __restrict__ W_gate, const float* __restrict__ W_out,
    const float* __restrict__ W_delta, const float* __restrict__ log_a,
    unsigned short* __restrict__ Wb, float* __restrict__ ea)
{
    int i = blockIdx.x * 256 + threadIdx.x;
    if (i < 5 * 65536) {
        int s = i >> 16, j = i & 65535;
        const float* src = (s == 0) ? W_delta : (s == 1) ? W_select
                         : (s == 2) ? W_in    : (s == 3) ? W_gate : W_out;
        Wb[i] = f2bf(src[j]);
    } else if (i < 5 * 65536 + 256) {
        int j = i - 5 * 65536;
        ea[j] = expf(log_a[j]);
    }
}

// --------------------------- gemm_du: delta/select/in + elementwise -------
// block = 256 thr (4 waves); wave = 64m x 32n x 3W (acc 96).
// block covers 64m x 128n; grid = 4096 m-tiles x 2 n-tiles.
// x fp32 -> bf16 converted in staging; LDS rows padded to 528B (no XOR).
// MFMA: A = W rows, B = x rows -> D col(lane&15)=m, D regs walk n.
__global__ __launch_bounds__(256, 3) void gemm_du_kernel(
    const float* __restrict__ x, const unsigned short* __restrict__ Wb,
    const float* __restrict__ ea, __half2* __restrict__ du)
{
    __shared__ unsigned short xls[64 * (ROWB / 2)];   // 33 KB
    int bid = blockIdx.x;
    int wg  = (bid & 7) * (8192 / 8) + (bid >> 3);    // bijective XCD swizzle
    int mtile = wg >> 1;
    int ntile = wg & 1;
    int tid  = threadIdx.x;
    int lane = tid & 63, wid = tid >> 6;
    int mbase = mtile * 64;

    // ---- stage + convert x-tile: 64 rows x 256 cols (2048 granules) ----
#pragma unroll
    for (int i = 0; i < 8; ++i) {
        int e = i * 256 + tid;
        int r = e >> 5, g = e & 31;
        s16x8 a = cvt8(x + (size_t)(mbase + r) * D_DIM + g * 8);
        *(s16x8*)((char*)xls + r * ROWB + g * 16) = a;
    }
    __syncthreads();

    int l16 = lane & 15;
    int lk  = lane >> 4;                 // 0..3
    int n0  = ntile * 128 + wid * 32;

    f32x4 acc[3][4][2] = {};             // [W][mf][nf]

    for (int ks = 0; ks < 8; ++ks) {
        int kb = ks * 32 + lk * 8;
        s16x8 xf[4];
#pragma unroll
        for (int mf = 0; mf < 4; ++mf)
            xf[mf] = *(const s16x8*)((const char*)xls + (mf * 16 + l16) * ROWB
                                     + (ks * 4 + lk) * 16);
#pragma unroll
        for (int w = 0; w < 3; ++w) {
#pragma unroll
            for (int nf = 0; nf < 2; ++nf) {
                s16x8 wfr = *(const s16x8*)(
                    Wb + ((size_t)w << 16) + (size_t)(n0 + nf * 16 + l16) * D_DIM + kb);
#pragma unroll
                for (int mf = 0; mf < 4; ++mf)
                    acc[w][mf][nf] = __builtin_amdgcn_mfma_f32_16x16x32_bf16(
                        wfr, xf[mf], acc[w][mf][nf], 0, 0, 0);
            }
        }
    }

    // epilogue: D col = lane&15 = m; D row = n = lk*4 + j
    int r0 = lk * 4;
#pragma unroll
    for (int mf = 0; mf < 4; ++mf) {
        int m = mbase + mf * 16 + l16;
#pragma unroll
        for (int nf = 0; nf < 2; ++nf) {
            int n = n0 + nf * 16 + r0;
            float4 eav = *(const float4*)(ea + n);
            __half2 dv[4];
#pragma unroll
            for (int j = 0; j < 4; ++j) {
                float ad = acc[0][mf][nf][j];
                float as = acc[1][mf][nf][j];
                float ai = acc[2][mf][nf][j];
                float e = __expf(ad);
                float delta = (ad > 15.f) ? ad : __logf(1.f + e);
                float ean = (j == 0) ? eav.x : (j == 1) ? eav.y : (j == 2) ? eav.z : eav.w;
                float dec = __expf(-delta * ean);
                float sel = 1.f / (1.f + __expf(-as));
                float upd = delta * sel * ai;
                dv[j] = __floats2half2_rn(dec, upd);
            }
            *(f32x4*)(du + (size_t)m * D_DIM + n) = *(f32x4*)dv;
        }
    }
}

// --------------------------- gemm_gate: gate projection + silu ------------
// block = 256 thr (4 waves); wave = 64m x 64n x 1W (acc 64); block = 64m x 256n.
__global__ __launch_bounds__(256, 4) void gemm_gate_kernel(
    const float* __restrict__ x, const unsigned short* __restrict__ Wg,
    unsigned short* __restrict__ gate)
{
    __shared__ unsigned short xls[64 * (ROWB / 2)];   // 33 KB
    int bid = blockIdx.x;
    int wg  = (bid & 7) * (4096 / 8) + (bid >> 3);
    int mbase = wg * 64;
    int tid  = threadIdx.x;
    int lane = tid & 63, wid = tid >> 6;

#pragma unroll
    for (int i = 0; i < 8; ++i) {
        int e = i * 256 + tid;
        int r = e >> 5, g = e & 31;
        s16x8 a = cvt8(x + (size_t)(mbase + r) * D_DIM + g * 8);
        *(s16x8*)((char*)xls + r * ROWB + g * 16) = a;
    }
    __syncthreads();

    int l16 = lane & 15;
    int lk  = lane >> 4;
    int n0  = wid * 64;

    f32x4 acc[4][4] = {};                // [mf][nf]

    for (int ks = 0; ks < 8; ++ks) {
        int kb = ks * 32 + lk * 8;
        s16x8 xf[4];
#pragma unroll
        for (int mf = 0; mf < 4; ++mf)
            xf[mf] = *(const s16x8*)((const char*)xls + (mf * 16 + l16) * ROWB
                                     + (ks * 4 + lk) * 16);
#pragma unroll
        for (int nf = 0; nf < 4; ++nf) {
            s16x8 wfr = *(const s16x8*)(
                Wg + (size_t)(n0 + nf * 16 + l16) * D_DIM + kb);
#pragma unroll
            for (int mf = 0; mf < 4; ++mf)
                acc[mf][nf] = __builtin_amdgcn_mfma_f32_16x16x32_bf16(
                    wfr, xf[mf], acc[mf][nf], 0, 0, 0);
        }
    }

    int r0 = lk * 4;
#pragma unroll
    for (int mf = 0; mf < 4; ++mf) {
        int m = mbase + mf * 16 + l16;
#pragma unroll
        for (int nf = 0; nf < 4; ++nf) {
            int n = n0 + nf * 16 + r0;
            u16x4 gv;
#pragma unroll
            for (int j = 0; j < 4; ++j) {
                float ag = acc[mf][nf][j];
                gv[j] = f2bf(ag / (1.f + __expf(-ag)));
            }
            *(u16x4*)(gate + (size_t)m * D_DIM + n) = gv;
        }
    }
}

// --------------------------- scan pass 1: chunk summaries ------------------
__global__ __launch_bounds__(256) void scan1_kernel(
    const __half2* __restrict__ du,
    float* __restrict__ cA, float* __restrict__ cS)
{
    int b = blockIdx.x >> 4;       // 128 batches
    int c = blockIdx.x & 15;       // 16 chunks
    int d = threadIdx.x;
    size_t base = ((size_t)b * T_DIM + (size_t)c * CLEN) * D_DIM + d;
    float A = 1.f, S = 0.f;
#pragma unroll 4
    for (int t = 0; t < CLEN; ++t) {
        __half2 v = du[base + (size_t)t * D_DIM];
        float dc = __low2float(v);
        float up = __high2float(v);
        A *= dc;
        S = fmaf(dc, S, up);
    }
    int idx = (b * NCHUNK + c) * D_DIM + d;
    cA[idx] = A;
    cS[idx] = S;
}

// --------------------------- scan pass 2: chunk carries --------------------
__global__ __launch_bounds__(256) void scan2_kernel(
    const float* __restrict__ cA, const float* __restrict__ cS,
    float* __restrict__ carry)
{
    int b = blockIdx.x;
    int d = threadIdx.x;
    float s = 0.f;
    for (int c = 0; c < NCHUNK; ++c) {
        int idx = (b * NCHUNK + c) * D_DIM + d;
        carry[idx] = s;                 // state entering chunk c
        s = fmaf(cA[idx], s, cS[idx]);
    }
}

// --------------------------- fused scan3 + out-projection ------------------
// block = (b, chunk): scans 128 t-rows (full D), builds y tile in LDS (bf16,
// chunk-XOR-swizzled), then computes out[128 x 256] = y @ Wo^T with MFMA.
__global__ __launch_bounds__(256) void scan_out_kernel(
    const __half2* __restrict__ du, const unsigned short* __restrict__ gate,
    const float* __restrict__ carry, const unsigned short* __restrict__ Wo,
    float* __restrict__ out)
{
    __shared__ unsigned short yls[128 * 256];   // 64 KB
    int b = blockIdx.x >> 4;
    int c = blockIdx.x & 15;
    int tid = threadIdx.x;

    // ---- phase 1: sequential scan, y -> LDS (swizzled 16B chunks) ----
    {
        int d = tid;
        size_t base = ((size_t)b * T_DIM + (size_t)c * CLEN) * D_DIM + d;
        float s = carry[(b * NCHUNK + c) * D_DIM + d];
        int dlo = d & 7, dch = d >> 3;
#pragma unroll 4
        for (int t = 0; t < CLEN; ++t) {
            __half2 v = du[base + (size_t)t * D_DIM];
            float dc = __low2float(v);
            float up = __high2float(v);
            s = fmaf(dc, s, up);
            float g = bf2f(gate[base + (size_t)t * D_DIM]);
            int off = t * 256 + ((dch ^ (t & 7)) << 3) + dlo;
            yls[off] = f2bf(s * g);
        }
    }
    __syncthreads();

    // ---- phase 2: out-tile GEMM, A-frag = Wo rows (global), B-frag = y (LDS)
    int lane = tid & 63, wid = tid >> 6;
    int l16 = lane & 15;
    int lkc = lane >> 4;            // k-subgroup 0..3
    int m0 = (wid >> 1) * 64;
    size_t rbase = (size_t)b * T_DIM + (size_t)c * CLEN;
    int r0 = lkc * 4;

    for (int nblk = 0; nblk < 2; ++nblk) {
        int n0 = (wid & 1) * 64 + nblk * 128;
        f32x4 acc[4][4] = {};
        for (int ks = 0; ks < 8; ++ks) {
            int kb = ks * 32 + lkc * 8;
            s16x8 yf[4];
#pragma unroll
            for (int mf = 0; mf < 4; ++mf) {
                int row = m0 + mf * 16 + l16;
                int chunk = (ks * 4 + lkc) ^ (row & 7);
                yf[mf] = *(const s16x8*)&yls[row * 256 + chunk * 8];
            }
#pragma unroll
            for (int nf = 0; nf < 4; ++nf) {
                s16x8 wfr = *(const s16x8*)(Wo + (size_t)(n0 + nf * 16 + l16) * D_DIM + kb);
#pragma unroll
                for (int mf = 0; mf < 4; ++mf)
                    acc[mf][nf] = __builtin_amdgcn_mfma_f32_16x16x32_bf16(
                        wfr, yf[mf], acc[mf][nf], 0, 0, 0);
            }
        }
        // D col = lane&15 = y row; D rows = n (4 consecutive) -> float4 stores
#pragma unroll
        for (int mf = 0; mf < 4; ++mf) {
            size_t rowg = rbase + m0 + mf * 16 + l16;
#pragma unroll
            for (int nf = 0; nf < 4; ++nf) {
                int n = n0 + nf * 16 + r0;
                *(f32x4*)(out + rowg * D_DIM + n) = acc[mf][nf];
            }
        }
    }
}

// ---------------------------------------------------------------------------
extern "C" void kernel_launch(void* const* d_in, const int* in_sizes, int n_in,
                              void* d_out, int out_size, void* d_ws, size_t ws_size,
                              hipStream_t stream)
{
    const float* x        = (const float*)d_in[0];
    const float* W_in     = (const float*)d_in[1];
    const float* W_select = (const float*)d_in[2];
    const float* W_gate   = (const float*)d_in[3];
    const float* W_out    = (const float*)d_in[4];
    const float* W_delta  = (const float*)d_in[5];
    const float* log_a    = (const float*)d_in[6];
    float* out = (float*)d_out;

    char* ws = (char*)d_ws;
    const size_t MB = 1ull << 20;
    unsigned short* Wb    = (unsigned short*)(ws);               // 640 KB
    float*          ea    = (float*)(ws + 655360);               // 1 KB
    __half2*        du    = (__half2*)(ws + 1 * MB);             // 256 MB
    unsigned short* gate  = (unsigned short*)(ws + 257 * MB);    // 128 MB
    float*          cA    = (float*)(ws + 385 * MB);             // 2 MB
    float*          cS    = (float*)(ws + 387 * MB);             // 2 MB
    float*          carry = (float*)(ws + 389 * MB);             // 2 MB
    // total: 391 MB

    prep_kernel<<<1281, 256, 0, stream>>>(W_in, W_select, W_gate, W_out,
                                          W_delta, log_a, Wb, ea);
    gemm_du_kernel<<<8192, 256, 0, stream>>>(x, Wb, ea, du);
    gemm_gate_kernel<<<4096, 256, 0, stream>>>(x, Wb + 3 * 65536, gate);
    scan1_kernel<<<B_DIM * NCHUNK, 256, 0, stream>>>(du, cA, cS);
    scan2_kernel<<<B_DIM, 256, 0, stream>>>(cA, cS, carry);
    scan_out_kernel<<<B_DIM * NCHUNK, 256, 0, stream>>>(du, gate, carry,
                                                        Wb + 4 * 65536, out);
}